// Round 4
// baseline (2153.601 us; speedup 1.0000x reference)
//
#include <hip/hip_runtime.h>
#include <stdint.h>

#define TT 1024
#define HB 256
#define BB 256
#define NE 48                       // per-row entry capacity (max row count; flag if exceeded)
#define O1 67108864u                // B*T*H
#define O2 (67108864u + 524288u)    // + B*T*2

__device__ __forceinline__ uint32_t rotl32(uint32_t x, uint32_t r){ return (x<<r)|(x>>(32u-r)); }

// Threefry-2x32, 20 rounds
__device__ __forceinline__ void tf2x32(uint32_t k0, uint32_t k1, uint32_t& x0, uint32_t& x1){
  const uint32_t ks2 = 0x1BD11BDAu ^ k0 ^ k1;
  x0 += k0; x1 += k1;
#define RND(r) { x0+=x1; x1=rotl32(x1,(r)); x1^=x0; }
  RND(13) RND(15) RND(26) RND(6)  x0+=k1;  x1+=ks2+1u;
  RND(17) RND(29) RND(16) RND(24) x0+=ks2; x1+=k0+2u;
  RND(13) RND(15) RND(26) RND(6)  x0+=k0;  x1+=k1+3u;
  RND(17) RND(29) RND(16) RND(24) x0+=k1;  x1+=ks2+4u;
  RND(13) RND(15) RND(26) RND(6)  x0+=ks2; x1+=k0+5u;
#undef RND
}

__device__ __forceinline__ float erfinv_f(float x){
  float w = -log1pf(-x*x);
  float p;
  if (w < 5.0f){
    w -= 2.5f;
    p = 2.81022636e-08f;
    p = fmaf(p, w, 3.43273939e-07f);
    p = fmaf(p, w, -3.5233877e-06f);
    p = fmaf(p, w, -4.39150654e-06f);
    p = fmaf(p, w, 0.00021858087f);
    p = fmaf(p, w, -0.00125372503f);
    p = fmaf(p, w, -0.00417768164f);
    p = fmaf(p, w, 0.246640727f);
    p = fmaf(p, w, 1.50140941f);
  } else {
    w = sqrtf(w) - 3.0f;
    p = -0.000200214257f;
    p = fmaf(p, w, 0.000100950558f);
    p = fmaf(p, w, 0.00134934322f);
    p = fmaf(p, w, -0.00367342844f);
    p = fmaf(p, w, 0.00573950773f);
    p = fmaf(p, w, -0.0076224613f);
    p = fmaf(p, w, 0.00943887047f);
    p = fmaf(p, w, 1.00167406f);
    p = fmaf(p, w, 2.83297682f);
  }
  return p * x;
}

__device__ __forceinline__ float bits_to_noise(uint32_t bits){
  float f = __uint_as_float((bits>>9) | 0x3F800000u) - 1.0f;
  const float lo = -0.99999994f;
  float u = fmaxf(fmaf(f, 1.99999994f, lo), lo);
  float r = 1.41421356237f * erfinv_f(u);
  return (r * 0.05f) * 0.5f;
}

__global__ void init_flags(uint32_t* flags){
  if (flags) { flags[0]=0u; flags[1]=0u; }
}

__global__ void check_kernel(float* out, const uint32_t* flags){
  uint32_t a0=0u, a1=0u;                 tf2x32(0u,0u,a0,a1);
  uint32_t b0=0xffffffffu, b1=0xffffffffu; tf2x32(0xffffffffu,0xffffffffu,b0,b1);
  uint32_t c0=0x243f6a88u, c1=0x85a308d3u; tf2x32(0x13198a2eu,0x03707344u,c0,c1);
  if (!(a0==0x6b200159u && a1==0x99ba4efeu)) out[0] = 1e30f;
  if (!(b0==0x1cb996fcu && b1==0xbb002be7u)) out[1] = 2e30f;
  if (!(c0==0xc4923a9cu && c1==0x483df7a0u)) out[2] = 3e30f;
  if (!(fabsf(erfinv_f(0.5f)   - 0.47693628f) < 1e-4f)) out[3] = 4e30f;
  if (!(fabsf(erfinv_f(0.999f) - 2.3267538f)  < 2e-3f)) out[4] = 5e30f;
  if (flags && flags[0]) out[5] = 6e30f;   // row entry-count overflow
}

__launch_bounds__(512, 2)
__global__ void rnn_kernel(const float* __restrict__ input_signal, // [B,T,2]
                           const float* __restrict__ hidden0,      // [B,H]
                           const float* __restrict__ w_in,         // [H,2]
                           const float* __restrict__ abs_w0,       // [H,H]
                           const float* __restrict__ w_sign,       // [H,H]
                           const float* __restrict__ is_con,       // [H,H]
                           float* __restrict__ out,
                           uint32_t* __restrict__ flags)
{
  __shared__ uint32_t ebuf[NE*HB];    // 48 KB: entry staging (init only)
  __shared__ float tbuf[2][HB];       // tanh double buffer
  __shared__ float nbuf[2][HB];       // noise double buffer (indexed by ROW)
  __shared__ int   cnts[HB];
  __shared__ int   rankinv[HB];

  const int tid  = threadIdx.x;
  const int lane = tid & 63;
  const int b    = blockIdx.x;
  const bool gw  = (tid < HB);        // gather waves 0-3; noise waves 4-7
  const int jj   = tid - HB;          // noise wave's row

  // ---------- one-time init ----------
  if (gw){
    int c0 = 0;
    const float* icrow = is_con + tid*HB;
    for (int k = 0; k < HB; k += 4){
      float4 c4 = *(const float4*)(icrow + k);
      c0 += (c4.x > 0.f) + (c4.y > 0.f) + (c4.z > 0.f) + (c4.w > 0.f);
    }
    cnts[tid] = c0;
  }
  __syncthreads();

  int jstar = 0, mycnt = 0;
  if (gw){
    int myc = cnts[tid];
    int rank = 0;
    for (int k = 0; k < HB; ++k){
      int ck = cnts[k];
      rank += (int)((ck > myc) || (ck == myc && k < tid));  // descending, tie by idx
    }
    rankinv[rank] = tid;
  }
  __syncthreads();

  uint32_t e[NE];
  int wtrip = 0;
  float wi0 = 0.f, wi1 = 0.f, h = 0.f;
  if (gw){
    jstar = rankinv[tid];
    mycnt = cnts[jstar];
    if (mycnt > NE){ if (flags) flags[0] = 1u; mycnt = NE; }

    // build entries for row jstar into ebuf column tid
    const float* icrow = is_con + jstar*HB;
    const float* awrow = abs_w0 + jstar*HB;
    const float* wsrow = w_sign + jstar*HB;
    int n = 0;
    for (int k = 0; k < HB; ++k){
      if (icrow[k] > 0.f && n < NE){
        float w = wsrow[k]*awrow[k];
        uint32_t ee = (__float_as_uint(w) + 0x80u) & 0xFFFFFF00u; // weight (16-bit mant trunc)
        ebuf[n*HB + tid] = ee | (uint32_t)k;                      // low 8 bits: source col
        ++n;
      }
    }
    // insertion-sort column by bank (idx & 31) — one-time, LDS-resident
    for (int a = 1; a < n; ++a){
      uint32_t v = ebuf[a*HB + tid]; uint32_t kb = v & 31u;
      int c = a - 1;
      while (c >= 0){
        uint32_t u2 = ebuf[c*HB + tid];
        if ((u2 & 31u) <= kb) break;
        ebuf[(c+1)*HB + tid] = u2; --c;
      }
      ebuf[(c+1)*HB + tid] = v;
    }
    // load to registers with lane-dependent rotation (spreads banks per slot)
    int rot = (lane * mycnt) >> 6;     // < mycnt
    #pragma unroll
    for (int s = 0; s < NE; ++s){
      uint32_t ee;
      if (s < mycnt){
        int p = s + rot; if (p >= mycnt) p -= mycnt;
        ee = ebuf[p*HB + tid];
      } else {
        ee = (uint32_t)(tid & 255);    // weight +0.0, spread dummy idx
      }
      e[s] = ee;
    }
    wtrip = __builtin_amdgcn_readfirstlane(mycnt);  // lane 0 = wave max (rank-sorted)

    wi0 = w_in[jstar*2 + 0]; wi1 = w_in[jstar*2 + 1];
    h   = hidden0[b*HB + jstar];
  } else {
    // noise prologue: t=0 values
    uint32_t x0 = 0u, x1 = (uint32_t)b*256u + (uint32_t)jj;
    tf2x32(0u, 42u, x0, x1);
    nbuf[0][jj] = bits_to_noise(x0 ^ x1);
  }

  const float* xin  = input_signal + (uint64_t)b*TT*2;
  float*       hrow = out + (uint64_t)b*TT*HB;

  for (int t = 0; t < TT; ++t){
    const int par = t & 1;
    float2 xv;
    if (gw){
      float th = 1.0f - 2.0f/(__expf(2.0f*h) + 1.0f);   // tanh(h)
      tbuf[par][jstar] = th;                            // scatter write (owner lane)
      xv = *(const float2*)(xin + t*2);                 // issue early; used post-gather
    }
    __syncthreads();                                    // the ONE barrier per step

    if (gw){
      const float* tb = tbuf[par];
      float y0 = 0.f, y1 = 0.f;
      #pragma unroll
      for (int s = 0; s < NE; ++s){
        if (s >= wtrip) break;                          // wave-uniform early exit
        uint32_t ee = e[s];
        float prod_w = __uint_as_float(ee & 0xFFFFFF00u);
        if (s & 1) y1 = fmaf(prod_w, tb[ee & 0xFFu], y1);
        else       y0 = fmaf(prod_w, tb[ee & 0xFFu], y0);
      }
      float y  = y0 + y1;
      float nz = nbuf[par][jstar];
      float u  = fmaf(xv.x, wi0, xv.y*wi1);
      h = fmaf(0.25f, u + y, 0.75f*h) + nz;
      hrow[t*HB + jstar] = h;
    } else if (t < TT-1){
      // produce noise for step t+1 (overlaps gather phase; read after next barrier)
      uint32_t x0 = 0u, x1 = (uint32_t)(t+1)*65536u + (uint32_t)b*256u + (uint32_t)jj;
      tf2x32(0u, 42u, x0, x1);
      nbuf[par ^ 1][jj] = bits_to_noise(x0 ^ x1);
    }
  }
  if (gw) out[O2 + b*HB + jstar] = h;
}

// Post-pass: output projection from hidden_list (full parallelism)
__global__ void outproj_kernel(const float* __restrict__ w_out,  // [2,H]
                               float* __restrict__ out)
{
  const int lane = threadIdx.x & 63;
  const int wv   = threadIdx.x >> 6;
  const float4 w0 = *(const float4*)(w_out + lane*4);
  const float4 w1 = *(const float4*)(w_out + HB + lane*4);
  const int wrow = blockIdx.x*4 + wv;          // 0..8191
  const float* hb = out;

  for (int it = 0; it < 32; ++it){
    int r = wrow*32 + it;                      // r = b*T + t
    const float4 v = *(const float4*)(hb + (uint64_t)r*HB + lane*4);
    float p0 = v.x*w0.x + v.y*w0.y + v.z*w0.z + v.w*w0.w;
    float p1 = v.x*w1.x + v.y*w1.y + v.z*w1.z + v.w*w1.w;
    #pragma unroll
    for (int m = 1; m < 64; m <<= 1){
      p0 += __shfl_xor(p0, m, 64);
      p1 += __shfl_xor(p1, m, 64);
    }
    if (lane == 0) *(float2*)(out + O1 + (uint64_t)r*2) = make_float2(p0, p1);
  }
}

extern "C" void kernel_launch(void* const* d_in, const int* in_sizes, int n_in,
                              void* d_out, int out_size, void* d_ws, size_t ws_size,
                              hipStream_t stream) {
  const float* input_signal = (const float*)d_in[0];
  const float* hidden       = (const float*)d_in[1];
  const float* w_in         = (const float*)d_in[2];
  const float* w_out        = (const float*)d_in[3];
  const float* abs_w0       = (const float*)d_in[4];
  const float* w_sign       = (const float*)d_in[5];
  const float* is_con       = (const float*)d_in[6];
  float* out = (float*)d_out;
  uint32_t* flags = (ws_size >= 8) ? (uint32_t*)d_ws : nullptr;

  init_flags<<<1, 1, 0, stream>>>(flags);
  rnn_kernel<<<BB, 512, 0, stream>>>(input_signal, hidden, w_in,
                                     abs_w0, w_sign, is_con, out, flags);
  outproj_kernel<<<2048, 256, 0, stream>>>(w_out, out);
  check_kernel<<<1, 1, 0, stream>>>(out, flags);
}

// Round 5
// 1431.955 us; speedup vs baseline: 1.5040x; 1.5040x over previous
//
#include <hip/hip_runtime.h>
#include <hip/hip_fp16.h>
#include <stdint.h>

#define TT 1024
#define HB 256
#define BB 256
#define NE 48                       // per-row entry capacity (flag if exceeded)
#define O1 67108864u                // B*T*H
#define O2 (67108864u + 524288u)    // + B*T*2

__device__ __forceinline__ uint32_t rotl32(uint32_t x, uint32_t r){ return (x<<r)|(x>>(32u-r)); }

// Threefry-2x32, 20 rounds
__device__ __forceinline__ void tf2x32(uint32_t k0, uint32_t k1, uint32_t& x0, uint32_t& x1){
  const uint32_t ks2 = 0x1BD11BDAu ^ k0 ^ k1;
  x0 += k0; x1 += k1;
#define RND(r) { x0+=x1; x1=rotl32(x1,(r)); x1^=x0; }
  RND(13) RND(15) RND(26) RND(6)  x0+=k1;  x1+=ks2+1u;
  RND(17) RND(29) RND(16) RND(24) x0+=ks2; x1+=k0+2u;
  RND(13) RND(15) RND(26) RND(6)  x0+=k0;  x1+=k1+3u;
  RND(17) RND(29) RND(16) RND(24) x0+=k1;  x1+=ks2+4u;
  RND(13) RND(15) RND(26) RND(6)  x0+=ks2; x1+=k0+5u;
#undef RND
}

__device__ __forceinline__ float erfinv_f(float x){
  float w = -log1pf(-x*x);
  float p;
  if (w < 5.0f){
    w -= 2.5f;
    p = 2.81022636e-08f;
    p = fmaf(p, w, 3.43273939e-07f);
    p = fmaf(p, w, -3.5233877e-06f);
    p = fmaf(p, w, -4.39150654e-06f);
    p = fmaf(p, w, 0.00021858087f);
    p = fmaf(p, w, -0.00125372503f);
    p = fmaf(p, w, -0.00417768164f);
    p = fmaf(p, w, 0.246640727f);
    p = fmaf(p, w, 1.50140941f);
  } else {
    w = sqrtf(w) - 3.0f;
    p = -0.000200214257f;
    p = fmaf(p, w, 0.000100950558f);
    p = fmaf(p, w, 0.00134934322f);
    p = fmaf(p, w, -0.00367342844f);
    p = fmaf(p, w, 0.00573950773f);
    p = fmaf(p, w, -0.0076224613f);
    p = fmaf(p, w, 0.00943887047f);
    p = fmaf(p, w, 1.00167406f);
    p = fmaf(p, w, 2.83297682f);
  }
  return p * x;
}

__device__ __forceinline__ float bits_to_noise(uint32_t bits){
  float f = __uint_as_float((bits>>9) | 0x3F800000u) - 1.0f;
  const float lo = -0.99999994f;
  float u = fmaxf(fmaf(f, 1.99999994f, lo), lo);
  float r = 1.41421356237f * erfinv_f(u);
  return (r * 0.05f) * 0.5f;
}

__global__ void init_flags(uint32_t* flags){
  if (flags) { flags[0]=0u; flags[1]=0u; }
}

__global__ void check_kernel(float* out, const uint32_t* flags){
  uint32_t a0=0u, a1=0u;                 tf2x32(0u,0u,a0,a1);
  uint32_t b0=0xffffffffu, b1=0xffffffffu; tf2x32(0xffffffffu,0xffffffffu,b0,b1);
  uint32_t c0=0x243f6a88u, c1=0x85a308d3u; tf2x32(0x13198a2eu,0x03707344u,c0,c1);
  if (!(a0==0x6b200159u && a1==0x99ba4efeu)) out[0] = 1e30f;
  if (!(b0==0x1cb996fcu && b1==0xbb002be7u)) out[1] = 2e30f;
  if (!(c0==0xc4923a9cu && c1==0x483df7a0u)) out[2] = 3e30f;
  if (!(fabsf(erfinv_f(0.5f)   - 0.47693628f) < 1e-4f)) out[3] = 4e30f;
  if (!(fabsf(erfinv_f(0.999f) - 2.3267538f)  < 2e-3f)) out[4] = 5e30f;
  if (flags && flags[0]) out[5] = 6e30f;   // row entry-count overflow
}

__launch_bounds__(512)
__global__ void rnn_kernel(const float* __restrict__ input_signal, // [B,T,2]
                           const float* __restrict__ hidden0,      // [B,H]
                           const float* __restrict__ w_in,         // [H,2]
                           const float* __restrict__ abs_w0,       // [H,H]
                           const float* __restrict__ w_sign,       // [H,H]
                           const float* __restrict__ is_con,       // [H,H]
                           float* __restrict__ out,
                           uint32_t* __restrict__ flags)
{
  __shared__ uint32_t ebuf[NE*HB];    // 48 KB: entry staging (init only)
  __shared__ float tbuf[2][HB];       // tanh double buffer (RANK-indexed)
  __shared__ float nbuf[2][HB];       // noise double buffer (RANK-indexed)
  __shared__ int   cnts[HB];
  __shared__ int   rankinv[HB];       // rank -> original row
  __shared__ int   rank_of[HB];       // original row -> rank

  const int tid  = threadIdx.x;
  const int b    = blockIdx.x;
  const bool gw  = (tid < HB);        // gather waves 0-3; noise waves 4-7
  const int jj   = tid - HB;          // noise lane's rank slot

  // ---------- one-time init: counts, ranks ----------
  if (gw){
    int c0 = 0;
    const float* icrow = is_con + tid*HB;
    for (int k = 0; k < HB; k += 4){
      float4 c4 = *(const float4*)(icrow + k);
      c0 += (c4.x > 0.f) + (c4.y > 0.f) + (c4.z > 0.f) + (c4.w > 0.f);
    }
    cnts[tid] = c0;
  }
  __syncthreads();
  if (gw){
    int myc = cnts[tid];
    int rank = 0;
    for (int k = 0; k < HB; ++k){
      int ck = cnts[k];
      rank += (int)((ck > myc) || (ck == myc && k < tid));  // descending, tie by idx
    }
    rankinv[rank] = tid;
    rank_of[tid]  = rank;
  }
  __syncthreads();

  // ---------- build packed entry lists ----------
  uint32_t pw[NE/2];                  // 2 fp16 weights per reg (24 regs)
  uint32_t pi[NE/4];                  // 4 u8 rank-indices per reg (12 regs)
  int wtrip = 0;
  int jstar = 0;
  float wi0 = 0.f, wi1 = 0.f, h = 0.f;
  int jorig_noise = 0;

  if (gw){
    jstar = rankinv[tid];
    int mycnt = cnts[jstar];
    if (mycnt > NE){ if (flags) flags[0] = 1u; mycnt = NE; }

    // stage into ebuf column tid: u32 = (fp16 weight << 16) | rank_idx
    for (int s = 0; s < NE; ++s)
      ebuf[s*HB + tid] = (uint32_t)(tid & 255);   // pad: weight fp16=0, spread idx
    const float* icrow = is_con + jstar*HB;
    const float* awrow = abs_w0 + jstar*HB;
    const float* wsrow = w_sign + jstar*HB;
    int n = 0;
    for (int k = 0; k < HB; ++k){
      if (icrow[k] > 0.f && n < NE){
        float w = wsrow[k]*awrow[k];
        uint32_t hw = (uint32_t)__half_as_ushort(__float2half(w));
        ebuf[n*HB + tid] = (hw << 16) | (uint32_t)rank_of[k];
        ++n;
      }
    }
    // pack to registers — fully static indexing
    #pragma unroll
    for (int q = 0; q < NE/4; ++q) pi[q] = 0u;
    #pragma unroll
    for (int s = 0; s < NE/2; ++s){
      uint32_t e0 = ebuf[(2*s)*HB + tid];
      uint32_t e1 = ebuf[(2*s+1)*HB + tid];
      pw[s] = (e0 >> 16) | (e1 & 0xFFFF0000u);
      pi[s>>1] |= ((e0 & 0xFFu) << (8*((s&1)*2))) | ((e1 & 0xFFu) << (8*((s&1)*2+1)));
    }
    wtrip = __builtin_amdgcn_readfirstlane(mycnt);  // lane 0 holds wave-max (rank-sorted)

    wi0 = w_in[jstar*2 + 0]; wi1 = w_in[jstar*2 + 1];
    h   = hidden0[b*HB + jstar];
    tbuf[0][tid] = 1.0f - 2.0f/(__expf(2.0f*h) + 1.0f);  // tanh(h0), rank slot
  } else {
    jorig_noise = rankinv[jj];
    // noise prologue: t=0 values
    uint32_t x0 = 0u, x1 = (uint32_t)b*256u + (uint32_t)jorig_noise;
    tf2x32(0u, 42u, x0, x1);
    nbuf[0][jj] = bits_to_noise(x0 ^ x1);
  }

  const float* xin  = input_signal + (uint64_t)b*TT*2;
  float*       hrow = out + (uint64_t)b*TT*HB;

  __syncthreads();

  for (int t = 0; t < TT; ++t){
    const int par = t & 1;
    if (gw){
      const float* tb = tbuf[par];
      float2 xv = *(const float2*)(xin + t*2);
      float y0 = 0.f, y1 = 0.f;
      #pragma unroll
      for (int s = 0; s < NE/2; ++s){
        if (2*s < wtrip){                       // wave-uniform guard, no break
          uint32_t pwv = pw[s];
          uint32_t piv = pi[s>>1] >> (16*(s&1));
          float w0 = __half2float(__ushort_as_half((unsigned short)(pwv & 0xFFFFu)));
          float w1 = __half2float(__ushort_as_half((unsigned short)(pwv >> 16)));
          y0 = fmaf(w0, tb[piv & 0xFFu], y0);
          y1 = fmaf(w1, tb[(piv >> 8) & 0xFFu], y1);
        }
      }
      float y  = y0 + y1;
      float nz = nbuf[par][tid];                // contiguous (rank slot)
      float u  = fmaf(xv.x, wi0, xv.y*wi1);
      h = fmaf(0.25f, u + y, 0.75f*h) + nz;
      hrow[t*HB + jstar] = h;                   // scattered, posted store
      tbuf[par ^ 1][tid] = 1.0f - 2.0f/(__expf(2.0f*h) + 1.0f);  // tanh for t+1
    } else if (t < TT-1){
      uint32_t x0 = 0u, x1 = (uint32_t)(t+1)*65536u + (uint32_t)b*256u + (uint32_t)jorig_noise;
      tf2x32(0u, 42u, x0, x1);
      nbuf[par ^ 1][jj] = bits_to_noise(x0 ^ x1);  // contiguous (rank slot)
    }
    __syncthreads();                            // the ONE barrier per step
  }
  if (gw) out[O2 + b*HB + jstar] = h;
}

// Post-pass: output projection from hidden_list (full parallelism)
__global__ void outproj_kernel(const float* __restrict__ w_out,  // [2,H]
                               float* __restrict__ out)
{
  const int lane = threadIdx.x & 63;
  const int wv   = threadIdx.x >> 6;
  const float4 w0 = *(const float4*)(w_out + lane*4);
  const float4 w1 = *(const float4*)(w_out + HB + lane*4);
  const int wrow = blockIdx.x*4 + wv;          // 0..8191
  const float* hb = out;

  for (int it = 0; it < 32; ++it){
    int r = wrow*32 + it;                      // r = b*T + t
    const float4 v = *(const float4*)(hb + (uint64_t)r*HB + lane*4);
    float p0 = v.x*w0.x + v.y*w0.y + v.z*w0.z + v.w*w0.w;
    float p1 = v.x*w1.x + v.y*w1.y + v.z*w1.z + v.w*w1.w;
    #pragma unroll
    for (int m = 1; m < 64; m <<= 1){
      p0 += __shfl_xor(p0, m, 64);
      p1 += __shfl_xor(p1, m, 64);
    }
    if (lane == 0) *(float2*)(out + O1 + (uint64_t)r*2) = make_float2(p0, p1);
  }
}

extern "C" void kernel_launch(void* const* d_in, const int* in_sizes, int n_in,
                              void* d_out, int out_size, void* d_ws, size_t ws_size,
                              hipStream_t stream) {
  const float* input_signal = (const float*)d_in[0];
  const float* hidden       = (const float*)d_in[1];
  const float* w_in         = (const float*)d_in[2];
  const float* w_out        = (const float*)d_in[3];
  const float* abs_w0       = (const float*)d_in[4];
  const float* w_sign       = (const float*)d_in[5];
  const float* is_con       = (const float*)d_in[6];
  float* out = (float*)d_out;
  uint32_t* flags = (ws_size >= 8) ? (uint32_t*)d_ws : nullptr;

  init_flags<<<1, 1, 0, stream>>>(flags);
  rnn_kernel<<<BB, 512, 0, stream>>>(input_signal, hidden, w_in,
                                     abs_w0, w_sign, is_con, out, flags);
  outproj_kernel<<<2048, 256, 0, stream>>>(w_out, out);
  check_kernel<<<1, 1, 0, stream>>>(out, flags);
}

// Round 6
// 1400.293 us; speedup vs baseline: 1.5380x; 1.0226x over previous
//
#include <hip/hip_runtime.h>
#include <hip/hip_fp16.h>
#include <stdint.h>

#define TT 1024
#define HB 256
#define BB 256
#define NE 48                       // per-row entry capacity (flag if exceeded)
#define O1 67108864u                // B*T*H
#define O2 (67108864u + 524288u)    // + B*T*2

__device__ __forceinline__ uint32_t rotl32(uint32_t x, uint32_t r){ return (x<<r)|(x>>(32u-r)); }

#define RND(r) { x0+=x1; x1=rotl32(x1,(r)); x1^=x0; }
// Threefry-2x32 split halves (rounds 1-12 / 13-20), generic key
__device__ __forceinline__ void tf_h1g(uint32_t k0,uint32_t k1,uint32_t ks2,uint32_t& x0,uint32_t& x1){
  x0 += k0; x1 += k1;
  RND(13) RND(15) RND(26) RND(6)  x0+=k1;  x1+=ks2+1u;
  RND(17) RND(29) RND(16) RND(24) x0+=ks2; x1+=k0+2u;
  RND(13) RND(15) RND(26) RND(6)  x0+=k0;  x1+=k1+3u;
}
__device__ __forceinline__ void tf_h2g(uint32_t k0,uint32_t k1,uint32_t ks2,uint32_t& x0,uint32_t& x1){
  RND(17) RND(29) RND(16) RND(24) x0+=k1;  x1+=ks2+4u;
  RND(13) RND(15) RND(26) RND(6)  x0+=ks2; x1+=k0+5u;
}
__device__ __forceinline__ void tf2x32(uint32_t k0,uint32_t k1,uint32_t& x0,uint32_t& x1){
  const uint32_t ks2 = 0x1BD11BDAu ^ k0 ^ k1;
  tf_h1g(k0,k1,ks2,x0,x1); tf_h2g(k0,k1,ks2,x0,x1);
}
// fixed key (0,42): ks2 = 0x1BD11BDA ^ 42 = 0x1BD11BF0
__device__ __forceinline__ void tf_h1(uint32_t& x0, uint32_t& x1){ tf_h1g(0u,42u,0x1BD11BF0u,x0,x1); }
__device__ __forceinline__ void tf_h2(uint32_t& x0, uint32_t& x1){ tf_h2g(0u,42u,0x1BD11BF0u,x0,x1); }
#undef RND

// uniform(-0.99999994,1) -> sqrt(2)*erfinv (Giles poly, HW log) -> *0.05*sqrt(0.25)
__device__ __forceinline__ float bits_to_noise(uint32_t bits){
  float f = __uint_as_float((bits>>9) | 0x3F800000u) - 1.0f;
  const float lo = -0.99999994f;
  float x = fmaxf(fmaf(f, 1.99999994f, lo), lo);
  float m = (1.0f - x) * (1.0f + x);              // 1-x^2, cancellation-free
  float w = -0.69314718056f * __log2f(m);         // v_log_f32, no libm call
  float p;
  if (w < 5.0f){
    w -= 2.5f;
    p = 2.81022636e-08f;
    p = fmaf(p, w, 3.43273939e-07f);
    p = fmaf(p, w, -3.5233877e-06f);
    p = fmaf(p, w, -4.39150654e-06f);
    p = fmaf(p, w, 0.00021858087f);
    p = fmaf(p, w, -0.00125372503f);
    p = fmaf(p, w, -0.00417768164f);
    p = fmaf(p, w, 0.246640727f);
    p = fmaf(p, w, 1.50140941f);
  } else {
    w = __fsqrt_rn(w) - 3.0f;
    p = -0.000200214257f;
    p = fmaf(p, w, 0.000100950558f);
    p = fmaf(p, w, 0.00134934322f);
    p = fmaf(p, w, -0.00367342844f);
    p = fmaf(p, w, 0.00573950773f);
    p = fmaf(p, w, -0.0076224613f);
    p = fmaf(p, w, 0.00943887047f);
    p = fmaf(p, w, 1.00167406f);
    p = fmaf(p, w, 2.83297682f);
  }
  return 0.035355339059f * (p * x);   // sqrt(2)*0.05*0.5
}

__global__ void init_flags(uint32_t* flags){
  if (flags) { flags[0]=0u; flags[1]=0u; }
}

__global__ void check_kernel(float* out, const uint32_t* flags){
  uint32_t a0=0u, a1=0u;                 tf2x32(0u,0u,a0,a1);
  uint32_t b0=0xffffffffu, b1=0xffffffffu; tf2x32(0xffffffffu,0xffffffffu,b0,b1);
  uint32_t c0=0x243f6a88u, c1=0x85a308d3u; tf2x32(0x13198a2eu,0x03707344u,c0,c1);
  if (!(a0==0x6b200159u && a1==0x99ba4efeu)) out[0] = 1e30f;
  if (!(b0==0x1cb996fcu && b1==0xbb002be7u)) out[1] = 2e30f;
  if (!(c0==0xc4923a9cu && c1==0x483df7a0u)) out[2] = 3e30f;
  // fixed-key halves must compose to the generic path
  uint32_t d0=7u, d1=9u; tf_h1(d0,d1); tf_h2(d0,d1);
  uint32_t e0=7u, e1=9u; tf2x32(0u,42u,e0,e1);
  if (!(d0==e0 && d1==e1)) out[3] = 4e30f;
  if (flags && flags[0]) out[5] = 6e30f;   // row entry-count overflow
}

__launch_bounds__(512)
__global__ void rnn_kernel(const float* __restrict__ input_signal, // [B,T,2]
                           const float* __restrict__ hidden0,      // [B,H]
                           const float* __restrict__ w_in,         // [H,2]
                           const float* __restrict__ abs_w0,       // [H,H]
                           const float* __restrict__ w_sign,       // [H,H]
                           const float* __restrict__ is_con,       // [H,H]
                           float* __restrict__ out,
                           uint32_t* __restrict__ flags)
{
  __shared__ uint32_t ebuf[NE*HB];    // 48 KB (init only)
  __shared__ float tbuf[2][HB];       // tanh double buffer (rank-indexed)
  __shared__ float nbuf[2][HB];       // noise double buffer (rank-indexed)
  __shared__ float xbuf[TT*2];        // 8 KB staged input row
  __shared__ float hstage[8][HB];     // 8 KB h staging (rank-indexed)
  __shared__ int   cnts[HB];
  __shared__ int   rankinv[HB];       // rank -> original row
  __shared__ int   rank_of[HB];       // original row -> rank

  const int tid  = threadIdx.x;
  const int b    = blockIdx.x;
  const bool gw  = (tid < HB);        // gather waves 0-3; noise waves 4-7
  const int jj   = tid - HB;          // noise lane's rank slot

  // ---------- one-time init ----------
  {
    const float* xg = input_signal + (uint64_t)b*TT*2;
    *(float4*)(xbuf + tid*4) = *(const float4*)(xg + tid*4);  // coalesced x stage
  }
  if (gw){
    int c0 = 0;
    const float* icrow = is_con + tid*HB;
    for (int k = 0; k < HB; k += 4){
      float4 c4 = *(const float4*)(icrow + k);
      c0 += (c4.x > 0.f) + (c4.y > 0.f) + (c4.z > 0.f) + (c4.w > 0.f);
    }
    cnts[tid] = c0;
  }
  __syncthreads();
  if (gw){
    int myc = cnts[tid];
    int rank = 0;
    for (int k = 0; k < HB; ++k){
      int ck = cnts[k];
      rank += (int)((ck > myc) || (ck == myc && k < tid));  // descending, tie by idx
    }
    rankinv[rank] = tid;
    rank_of[tid]  = rank;
  }
  __syncthreads();

  uint32_t pw[NE/2];                  // 2 fp16 weights per reg
  uint32_t pi[NE/4];                  // 4 u8 rank-indices per reg
  int wtrip = 0, jstar = 0;
  float wi0 = 0.f, wi1 = 0.f, h = 0.f;
  uint32_t ax0 = 0u, ax1 = 0u, bj = 0u;

  if (gw){
    jstar = rankinv[tid];
    int mycnt = cnts[jstar];
    if (mycnt > NE){ if (flags) flags[0] = 1u; mycnt = NE; }

    for (int s = 0; s < NE; ++s)
      ebuf[s*HB + tid] = (uint32_t)(tid & 255);   // pad: fp16 weight 0, spread idx
    const float* icrow = is_con + jstar*HB;
    const float* awrow = abs_w0 + jstar*HB;
    const float* wsrow = w_sign + jstar*HB;
    int n = 0;
    for (int k = 0; k < HB; ++k){
      if (icrow[k] > 0.f && n < NE){
        float w = wsrow[k]*awrow[k];
        uint32_t hw = (uint32_t)__half_as_ushort(__float2half(w));
        ebuf[n*HB + tid] = (hw << 16) | (uint32_t)rank_of[k];
        ++n;
      }
    }
    #pragma unroll
    for (int q = 0; q < NE/4; ++q) pi[q] = 0u;
    #pragma unroll
    for (int s = 0; s < NE/2; ++s){
      uint32_t e0 = ebuf[(2*s)*HB + tid];
      uint32_t e1 = ebuf[(2*s+1)*HB + tid];
      pw[s] = (e0 >> 16) | (e1 & 0xFFFF0000u);
      pi[s>>1] |= ((e0 & 0xFFu) << (8*((s&1)*2))) | ((e1 & 0xFFu) << (8*((s&1)*2+1)));
    }
    wtrip = __builtin_amdgcn_readfirstlane(mycnt);

    wi0 = w_in[jstar*2 + 0]; wi1 = w_in[jstar*2 + 1];
    h   = hidden0[b*HB + jstar];
    tbuf[0][tid] = 1.0f - 2.0f/(__expf(2.0f*h) + 1.0f);
  } else {
    int jorig = rankinv[jj];
    bj = (uint32_t)b*256u + (uint32_t)jorig;
    // n(0) full
    uint32_t x0 = 0u, x1 = bj;
    tf2x32(0u, 42u, x0, x1);
    nbuf[0][jj] = bits_to_noise(x0 ^ x1);
    // start chain for n(1): rounds 1-12
    ax0 = 0u; ax1 = 65536u + bj;
    tf_h1(ax0, ax1);
  }

  float* hrow = out + (uint64_t)b*TT*HB;
  __syncthreads();

  for (int t = 0; t < TT; ++t){
    const int par = t & 1;
    if (gw){
      const float* tb = tbuf[par];
      float2 xv = *(const float2*)(xbuf + t*2);   // LDS broadcast
      float y0 = 0.f, y1 = 0.f;
      #pragma unroll
      for (int s = 0; s < NE/2; ++s){
        if (2*s < wtrip){                          // wave-uniform guard
          uint32_t pwv = pw[s];
          uint32_t piv = pi[s>>1] >> (16*(s&1));
          float w0 = __half2float(__ushort_as_half((unsigned short)(pwv & 0xFFFFu)));
          float w1 = __half2float(__ushort_as_half((unsigned short)(pwv >> 16)));
          y0 = fmaf(w0, tb[piv & 0xFFu], y0);
          y1 = fmaf(w1, tb[(piv >> 8) & 0xFFu], y1);
        }
      }
      float nz = nbuf[par][tid];                   // contiguous (rank slot)
      float u  = fmaf(xv.x, wi0, xv.y*wi1);
      h = fmaf(0.25f, u + y0 + y1, 0.75f*h) + nz;
      hstage[t & 7][tid] = h;                      // contiguous LDS stage
      tbuf[par ^ 1][tid] = 1.0f - 2.0f/(__expf(2.0f*h) + 1.0f);
    } else {
      if (t < TT-1){                               // finish n(t+1): rounds 13-20
        uint32_t f0 = ax0, f1 = ax1;
        tf_h2(f0, f1);
        nbuf[par ^ 1][jj] = bits_to_noise(f0 ^ f1);
      }
      if (t < TT-2){                               // start n(t+2): rounds 1-12
        ax0 = 0u; ax1 = (uint32_t)(t+2)*65536u + bj;
        tf_h1(ax0, ax1);
      }
    }
    __syncthreads();                               // one barrier per step

    if ((t & 7) == 7){                             // cooperative coalesced flush
      int r  = tid >> 6;                           // wave -> row of octave
      int j0 = (tid & 63) << 2;
      const int4 rk = *(const int4*)(rank_of + j0);
      float4 v;
      v.x = hstage[r][rk.x]; v.y = hstage[r][rk.y];
      v.z = hstage[r][rk.z]; v.w = hstage[r][rk.w];
      *(float4*)(hrow + (uint64_t)(t - 7 + r)*HB + j0) = v;
    }
  }
  if (gw) out[O2 + b*HB + jstar] = h;
}

// Post-pass: output projection from hidden_list (full parallelism)
__global__ void outproj_kernel(const float* __restrict__ w_out,  // [2,H]
                               float* __restrict__ out)
{
  const int lane = threadIdx.x & 63;
  const int wv   = threadIdx.x >> 6;
  const float4 w0 = *(const float4*)(w_out + lane*4);
  const float4 w1 = *(const float4*)(w_out + HB + lane*4);
  const int wrow = blockIdx.x*4 + wv;          // 0..8191
  const float* hb = out;

  for (int it = 0; it < 32; ++it){
    int r = wrow*32 + it;                      // r = b*T + t
    const float4 v = *(const float4*)(hb + (uint64_t)r*HB + lane*4);
    float p0 = v.x*w0.x + v.y*w0.y + v.z*w0.z + v.w*w0.w;
    float p1 = v.x*w1.x + v.y*w1.y + v.z*w1.z + v.w*w1.w;
    #pragma unroll
    for (int m = 1; m < 64; m <<= 1){
      p0 += __shfl_xor(p0, m, 64);
      p1 += __shfl_xor(p1, m, 64);
    }
    if (lane == 0) *(float2*)(out + O1 + (uint64_t)r*2) = make_float2(p0, p1);
  }
}

extern "C" void kernel_launch(void* const* d_in, const int* in_sizes, int n_in,
                              void* d_out, int out_size, void* d_ws, size_t ws_size,
                              hipStream_t stream) {
  const float* input_signal = (const float*)d_in[0];
  const float* hidden       = (const float*)d_in[1];
  const float* w_in         = (const float*)d_in[2];
  const float* w_out        = (const float*)d_in[3];
  const float* abs_w0       = (const float*)d_in[4];
  const float* w_sign       = (const float*)d_in[5];
  const float* is_con       = (const float*)d_in[6];
  float* out = (float*)d_out;
  uint32_t* flags = (ws_size >= 8) ? (uint32_t*)d_ws : nullptr;

  init_flags<<<1, 1, 0, stream>>>(flags);
  rnn_kernel<<<BB, 512, 0, stream>>>(input_signal, hidden, w_in,
                                     abs_w0, w_sign, is_con, out, flags);
  outproj_kernel<<<2048, 256, 0, stream>>>(w_out, out);
  check_kernel<<<1, 1, 0, stream>>>(out, flags);
}

// Round 7
// 947.971 us; speedup vs baseline: 2.2718x; 1.4771x over previous
//
#include <hip/hip_runtime.h>
#include <hip/hip_fp16.h>
#include <stdint.h>

#define TT 1024
#define HB 256
#define BB 256
#define NE2 24                      // per-LANE entry slots (2 lanes/row -> row cap 48)
#define O1 67108864u                // B*T*H
#define O2 (67108864u + 524288u)    // + B*T*2

__device__ __forceinline__ uint32_t rotl32(uint32_t x, uint32_t r){ return (x<<r)|(x>>(32u-r)); }

#define RND(r) { x0+=x1; x1=rotl32(x1,(r)); x1^=x0; }
__device__ __forceinline__ void tf2x32(uint32_t k0,uint32_t k1,uint32_t& x0,uint32_t& x1){
  const uint32_t ks2 = 0x1BD11BDAu ^ k0 ^ k1;
  x0 += k0; x1 += k1;
  RND(13) RND(15) RND(26) RND(6)  x0+=k1;  x1+=ks2+1u;
  RND(17) RND(29) RND(16) RND(24) x0+=ks2; x1+=k0+2u;
  RND(13) RND(15) RND(26) RND(6)  x0+=k0;  x1+=k1+3u;
  RND(17) RND(29) RND(16) RND(24) x0+=k1;  x1+=ks2+4u;
  RND(13) RND(15) RND(26) RND(6)  x0+=ks2; x1+=k0+5u;
}
#undef RND

// uniform(-0.99999994,1) -> sqrt(2)*erfinv (Giles poly, HW log) -> *0.05*0.5
__device__ __forceinline__ float bits_to_noise(uint32_t bits){
  float f = __uint_as_float((bits>>9) | 0x3F800000u) - 1.0f;
  const float lo = -0.99999994f;
  float x = fmaxf(fmaf(f, 1.99999994f, lo), lo);
  float m = (1.0f - x) * (1.0f + x);              // 1-x^2, cancellation-free
  float w = -0.69314718056f * __log2f(m);
  float p;
  if (w < 5.0f){
    w -= 2.5f;
    p = 2.81022636e-08f;
    p = fmaf(p, w, 3.43273939e-07f);
    p = fmaf(p, w, -3.5233877e-06f);
    p = fmaf(p, w, -4.39150654e-06f);
    p = fmaf(p, w, 0.00021858087f);
    p = fmaf(p, w, -0.00125372503f);
    p = fmaf(p, w, -0.00417768164f);
    p = fmaf(p, w, 0.246640727f);
    p = fmaf(p, w, 1.50140941f);
  } else {
    w = __fsqrt_rn(w) - 3.0f;
    p = -0.000200214257f;
    p = fmaf(p, w, 0.000100950558f);
    p = fmaf(p, w, 0.00134934322f);
    p = fmaf(p, w, -0.00367342844f);
    p = fmaf(p, w, 0.00573950773f);
    p = fmaf(p, w, -0.0076224613f);
    p = fmaf(p, w, 0.00943887047f);
    p = fmaf(p, w, 1.00167406f);
    p = fmaf(p, w, 2.83297682f);
  }
  return 0.035355339059f * (p * x);   // sqrt(2)*0.05*0.5
}

__global__ void init_flags(uint32_t* flags){
  if (flags) { flags[0]=0u; flags[1]=0u; }
}

__global__ void check_kernel(float* out, const uint32_t* flags){
  uint32_t a0=0u, a1=0u;                 tf2x32(0u,0u,a0,a1);
  uint32_t b0=0xffffffffu, b1=0xffffffffu; tf2x32(0xffffffffu,0xffffffffu,b0,b1);
  uint32_t c0=0x243f6a88u, c1=0x85a308d3u; tf2x32(0x13198a2eu,0x03707344u,c0,c1);
  if (!(a0==0x6b200159u && a1==0x99ba4efeu)) out[0] = 1e30f;
  if (!(b0==0x1cb996fcu && b1==0xbb002be7u)) out[1] = 2e30f;
  if (!(c0==0xc4923a9cu && c1==0x483df7a0u)) out[2] = 3e30f;
  if (flags && flags[0]) out[5] = 6e30f;   // row entry-count overflow
}

__launch_bounds__(1024, 4)
__global__ void rnn_kernel(const float* __restrict__ input_signal, // [B,T,2]
                           const float* __restrict__ hidden0,      // [B,H]
                           const float* __restrict__ w_in,         // [H,2]
                           const float* __restrict__ abs_w0,       // [H,H]
                           const float* __restrict__ w_sign,       // [H,H]
                           const float* __restrict__ is_con,       // [H,H]
                           float* __restrict__ out,
                           uint32_t* __restrict__ flags)
{
  __shared__ uint32_t ebuf[NE2*512];  // 48 KB (init only)
  __shared__ float tbuf[2][HB];       // tanh double buffer (rank-indexed)
  __shared__ float nbuf[4][HB];       // noise ring (rank-indexed)
  __shared__ float xbuf[TT*2];        // 8 KB staged input row
  __shared__ float hstage[8][HB];     // 8 KB h staging (rank-indexed)
  __shared__ int   cnts[HB];
  __shared__ int   rankinv[HB];       // rank -> original row
  __shared__ int   rank_of[HB];       // original row -> rank

  const int tid = threadIdx.x;
  const int b   = blockIdx.x;
  const bool gw = (tid < 512);        // waves 0-7 gather; 8-15 noise

  // ---- phase A: x stage + row counts ----
  if (tid < 512){
    const float* xg = input_signal + (uint64_t)b*TT*2;
    *(float4*)(xbuf + tid*4) = *(const float4*)(xg + tid*4);
  }
  if (tid < HB){
    int c0 = 0;
    const float* icrow = is_con + tid*HB;
    for (int k = 0; k < HB; k += 4){
      float4 c4 = *(const float4*)(icrow + k);
      c0 += (c4.x > 0.f) + (c4.y > 0.f) + (c4.z > 0.f) + (c4.w > 0.f);
    }
    cnts[tid] = c0;
  }
  __syncthreads();

  // ---- phase B: ranks (descending count) ----
  if (tid < HB){
    int myc = cnts[tid];
    int rank = 0;
    for (int k = 0; k < HB; ++k){
      int ck = cnts[k];
      rank += (int)((ck > myc) || (ck == myc && k < tid));
    }
    rankinv[rank] = tid;
    rank_of[tid]  = rank;
  }
  __syncthreads();

  // ---- phase C: build entry columns (parity-0 lane builds both) + noise t=0 ----
  int rr = 0, q = 0, jstar = 0;
  uint32_t bj = 0u;                   // noise lanes: b*256 + jorig
  if (gw){
    rr = tid >> 1; q = tid & 1;
    jstar = rankinv[rr];
    if (q == 0){
      int cnt = cnts[jstar];
      if (cnt > 2*NE2 && flags) flags[0] = 1u;
      const float* icrow = is_con + jstar*HB;
      const float* awrow = abs_w0 + jstar*HB;
      const float* wsrow = w_sign + jstar*HB;
      int seq = 0;
      for (int k = 0; k < HB; ++k){
        if (icrow[k] > 0.f && seq < 2*NE2){
          float w = wsrow[k]*awrow[k];
          uint32_t hw = (uint32_t)__half_as_ushort(__float2half(w));
          uint32_t e  = (hw << 16) | (uint32_t)rank_of[k];
          ebuf[(seq>>1)*512 + tid + (seq&1)] = e;
          ++seq;
        }
      }
      int nE = (seq+1)>>1, nO = seq>>1;
      for (int s = nE; s < NE2; ++s) ebuf[s*512 + tid]     = (uint32_t)(tid & 255);
      for (int s = nO; s < NE2; ++s) ebuf[s*512 + tid + 1] = (uint32_t)(tid & 255);
    }
  } else {
    int n = tid - 512, rn = n>>1, qn = n&1;
    bj = (uint32_t)b*256u + (uint32_t)rankinv[rn];
    if (qn == 0){
      uint32_t x0 = 0u, x1 = bj;
      tf2x32(0u, 42u, x0, x1);
      nbuf[0][rn] = bits_to_noise(x0 ^ x1);
    }
  }
  __syncthreads();

  // ---- phase D: pack registers, load per-row state ----
  uint32_t pw[NE2/2];                 // 2 fp16 weights / reg
  uint32_t pi[NE2/4];                 // 4 u8 rank-indices / reg
  int wtrip = 0;
  float wi0 = 0.f, wi1 = 0.f, h = 0.f;
  if (gw){
    #pragma unroll
    for (int s2 = 0; s2 < NE2/4; ++s2) pi[s2] = 0u;
    #pragma unroll
    for (int s = 0; s < NE2/2; ++s){
      uint32_t e0 = ebuf[(2*s)*512 + tid];
      uint32_t e1 = ebuf[(2*s+1)*512 + tid];
      pw[s] = (e0 >> 16) | (e1 & 0xFFFF0000u);
      pi[s>>1] |= ((e0 & 0xFFu) << (8*((s&1)*2))) | ((e1 & 0xFFu) << (8*((s&1)*2+1)));
    }
    wtrip = __builtin_amdgcn_readfirstlane((cnts[jstar]+1) >> 1);  // lane0 = wave max
    if (q == 0){
      wi0 = w_in[jstar*2 + 0]; wi1 = w_in[jstar*2 + 1];
      h   = hidden0[b*HB + jstar];
      tbuf[0][rr] = 1.0f - 2.0f/(__expf(2.0f*h) + 1.0f);
    }
  }
  float* hrow = out + (uint64_t)b*TT*HB;
  __syncthreads();

  // ---- main loop: one barrier per step ----
  for (int t = 0; t < TT; ++t){
    const int par = t & 1;
    if (gw){
      const float* tb = tbuf[par];
      float y0 = 0.f, y1 = 0.f;
      #pragma unroll
      for (int s = 0; s < NE2/2; ++s){
        if (2*s < wtrip){                          // wave-uniform guard
          uint32_t pwv = pw[s];
          uint32_t piv = pi[s>>1] >> (16*(s&1));
          float w0 = __half2float(__ushort_as_half((unsigned short)(pwv & 0xFFFFu)));
          float w1 = __half2float(__ushort_as_half((unsigned short)(pwv >> 16)));
          y0 = fmaf(w0, tb[piv & 0xFFu], y0);
          y1 = fmaf(w1, tb[(piv >> 8) & 0xFFu], y1);
        }
      }
      float y = y0 + y1;
      y += __shfl_xor(y, 1, 64);                   // combine row halves
      if (q == 0){
        float nz = nbuf[t & 3][rr];
        float2 xv = *(const float2*)(xbuf + t*2);
        float u  = fmaf(xv.x, wi0, xv.y*wi1);
        h = fmaf(0.25f, u + y, 0.75f*h) + nz;
        hstage[t & 7][rr] = h;
        tbuf[par ^ 1][rr] = 1.0f - 2.0f/(__expf(2.0f*h) + 1.0f);
      }
    } else {
      if ((t & 1) == 0){
        int n = tid - 512, rn = n>>1, qn = n&1;
        int tv = t + 1 + qn;
        if (tv < TT){
          uint32_t x0 = 0u, x1 = (uint32_t)tv*65536u + bj;
          tf2x32(0u, 42u, x0, x1);
          nbuf[tv & 3][rn] = bits_to_noise(x0 ^ x1);
        }
      }
    }
    __syncthreads();                               // one barrier per step

    if ((t & 7) == 7){                             // coalesced flush, overlaps next step
      int fr = tid >> 7;                           // 0..7
      int j0 = (tid & 127) << 1;
      float2 v;
      v.x = hstage[fr][rank_of[j0]];
      v.y = hstage[fr][rank_of[j0+1]];
      *(float2*)(hrow + (uint64_t)(t - 7 + fr)*HB + j0) = v;
    }
  }
  if (gw && q == 0) out[O2 + b*HB + jstar] = h;
}

// Post-pass: output projection from hidden_list (full parallelism)
__global__ void outproj_kernel(const float* __restrict__ w_out,  // [2,H]
                               float* __restrict__ out)
{
  const int lane = threadIdx.x & 63;
  const int wv   = threadIdx.x >> 6;
  const float4 w0 = *(const float4*)(w_out + lane*4);
  const float4 w1 = *(const float4*)(w_out + HB + lane*4);
  const int wrow = blockIdx.x*4 + wv;          // 0..8191
  const float* hb = out;

  for (int it = 0; it < 32; ++it){
    int r = wrow*32 + it;                      // r = b*T + t
    const float4 v = *(const float4*)(hb + (uint64_t)r*HB + lane*4);
    float p0 = v.x*w0.x + v.y*w0.y + v.z*w0.z + v.w*w0.w;
    float p1 = v.x*w1.x + v.y*w1.y + v.z*w1.z + v.w*w1.w;
    #pragma unroll
    for (int m = 1; m < 64; m <<= 1){
      p0 += __shfl_xor(p0, m, 64);
      p1 += __shfl_xor(p1, m, 64);
    }
    if (lane == 0) *(float2*)(out + O1 + (uint64_t)r*2) = make_float2(p0, p1);
  }
}

extern "C" void kernel_launch(void* const* d_in, const int* in_sizes, int n_in,
                              void* d_out, int out_size, void* d_ws, size_t ws_size,
                              hipStream_t stream) {
  const float* input_signal = (const float*)d_in[0];
  const float* hidden       = (const float*)d_in[1];
  const float* w_in         = (const float*)d_in[2];
  const float* w_out        = (const float*)d_in[3];
  const float* abs_w0       = (const float*)d_in[4];
  const float* w_sign       = (const float*)d_in[5];
  const float* is_con       = (const float*)d_in[6];
  float* out = (float*)d_out;
  uint32_t* flags = (ws_size >= 8) ? (uint32_t*)d_ws : nullptr;

  init_flags<<<1, 1, 0, stream>>>(flags);
  rnn_kernel<<<BB, 1024, 0, stream>>>(input_signal, hidden, w_in,
                                      abs_w0, w_sign, is_con, out, flags);
  outproj_kernel<<<2048, 256, 0, stream>>>(w_out, out);
  check_kernel<<<1, 1, 0, stream>>>(out, flags);
}